// Round 10
// baseline (204.074 us; speedup 1.0000x reference)
//
#include <hip/hip_runtime.h>

typedef __bf16 bf16;
using bf16x2 = __attribute__((ext_vector_type(2))) bf16;
using bf16x4 = __attribute__((ext_vector_type(4))) bf16;
using bf16x8 = __attribute__((ext_vector_type(8))) bf16;
using f32x4  = __attribute__((ext_vector_type(4))) float;

#define DEVI __device__ __forceinline__

DEVI void gload_lds16(const void* g, void* l) {
  __builtin_amdgcn_global_load_lds((const __attribute__((address_space(1))) void*)g,
                                   (__attribute__((address_space(3))) void*)l, 16, 0, 0);
}

DEVI float exp2_fast(float x) { return __builtin_amdgcn_exp2f(x); }  // v_exp_f32

// ---------------- fp32 -> bf16 convert, all three inputs in one launch -----
__global__ __launch_bounds__(256) void k_cvt3(
    const float* __restrict__ a, bf16* __restrict__ oa,
    const float* __restrict__ b, bf16* __restrict__ ob,
    const float* __restrict__ c, bf16* __restrict__ oc) {
  const int blk = blockIdx.x;
  const float* in; bf16* out; int i;
  if (blk < 4096)      { in = a; out = oa; i = blk * 256 + threadIdx.x; }
  else if (blk < 7168) { in = b; out = ob; i = (blk - 4096) * 256 + threadIdx.x; }
  else                 { in = c; out = oc; i = (blk - 7168) * 256 + threadIdx.x; }
  f32x4 v = ((const f32x4*)in)[i];
  bf16x4 o = {(bf16)v.x, (bf16)v.y, (bf16)v.z, (bf16)v.w};
  ((bf16x4*)out)[i] = o;
}

// ---------------- GEMM: out[m,n] = sum_k A[m,k]*W[n,k] (+bias) ------------
// 128x128 tile, BK=32, 4 waves (2x2 of 64x64), global_load_lds width=16.
// XCD-bijective block swizzle (grid count % 8 == 0) for B-panel L2 reuse.
template<int OUT_BF16, int HAS_BIAS>
__global__ __launch_bounds__(256) void k_gemm_bt(
    const bf16* __restrict__ A, const bf16* __restrict__ W,
    const float* __restrict__ bias, void* __restrict__ outp,
    int Kk, int Nout)
{
  __shared__ __align__(16) bf16 As[128 * 32];
  __shared__ __align__(16) bf16 Bs[128 * 32];
  const int t = threadIdx.x;
  const int lane = t & 63, wv = t >> 6;
  const int l15 = lane & 15, l4 = lane >> 4;
  // XCD swizzle: fb -> (xcd = fb&7) gets contiguous chunk of cpx blocks
  const int nbx = gridDim.x;
  const int fb = blockIdx.y * nbx + blockIdx.x;
  const int cpx = (nbx * gridDim.y) >> 3;
  const int swz = (fb & 7) * cpx + (fb >> 3);
  const int row0 = (swz % nbx) * 128, col0 = (swz / nbx) * 128;
  const int wr = wv >> 1, wc = wv & 1;

  f32x4 acc[4][4];
  #pragma unroll
  for (int m = 0; m < 4; ++m)
    #pragma unroll
    for (int n = 0; n < 4; ++n) acc[m][n] = (f32x4){0.f, 0.f, 0.f, 0.f};

  // staging: 512 chunks of 16B per 128x32 tile; thread t owns chunks t, t+256
  const int g0 = t, g1 = t + 256;
  const bf16* ga0 = A + (size_t)(row0 + (g0 >> 2)) * Kk + (g0 & 3) * 8;
  const bf16* ga1 = A + (size_t)(row0 + (g1 >> 2)) * Kk + (g1 & 3) * 8;
  const bf16* gb0 = W + (size_t)(col0 + (g0 >> 2)) * Kk + (g0 & 3) * 8;
  const bf16* gb1 = W + (size_t)(col0 + (g1 >> 2)) * Kk + (g1 & 3) * 8;
  // wave-uniform LDS bases (lane*16 is added by HW)
  char* la0 = (char*)As + wv * 1024;
  char* la1 = (char*)As + 4096 + wv * 1024;
  char* lb0 = (char*)Bs + wv * 1024;
  char* lb1 = (char*)Bs + 4096 + wv * 1024;

  const int nk = Kk >> 5;
  for (int kt = 0; kt < nk; ++kt) {
    __syncthreads();
    gload_lds16(ga0 + kt * 32, la0);
    gload_lds16(ga1 + kt * 32, la1);
    gload_lds16(gb0 + kt * 32, lb0);
    gload_lds16(gb1 + kt * 32, lb1);
    __syncthreads();
    bf16x8 af[4], bfv[4];
    #pragma unroll
    for (int m = 0; m < 4; ++m)
      af[m] = *(const bf16x8*)(As + (wr * 64 + m * 16 + l15) * 32 + l4 * 8);
    #pragma unroll
    for (int n = 0; n < 4; ++n)
      bfv[n] = *(const bf16x8*)(Bs + (wc * 64 + n * 16 + l15) * 32 + l4 * 8);
    #pragma unroll
    for (int m = 0; m < 4; ++m)
      #pragma unroll
      for (int n = 0; n < 4; ++n)
        acc[m][n] = __builtin_amdgcn_mfma_f32_16x16x32_bf16(af[m], bfv[n], acc[m][n], 0, 0, 0);
  }

  // epilogue: D[row=(l>>4)*4+r][col=l&15] (m89-verified mapping)
  #pragma unroll
  for (int n = 0; n < 4; ++n) {
    const int col = col0 + wc * 64 + n * 16 + l15;
    float bv = HAS_BIAS ? bias[col] : 0.f;
    #pragma unroll
    for (int m = 0; m < 4; ++m) {
      #pragma unroll
      for (int r = 0; r < 4; ++r) {
        const int row = row0 + wr * 64 + m * 16 + l4 * 4 + r;
        float v = acc[m][n][r] + bv;
        if (OUT_BF16) ((bf16*)outp)[(size_t)row * Nout + col] = (bf16)v;
        else          ((float*)outp)[(size_t)row * Nout + col] = v;
      }
    }
  }
}

// ---------------- per-row L2 norm of q and k (one wave per row) -----------
__global__ __launch_bounds__(256) void k_rownorm(const bf16* __restrict__ qkv,
                                                 float* __restrict__ invq,
                                                 float* __restrict__ invk)
{
  const int row = blockIdx.x * 4 + (threadIdx.x >> 6);
  const int lane = threadIdx.x & 63;
  const bf16* p = qkv + (size_t)row * 3072 + lane * 16;
  float sq = 0.f, sk = 0.f;
  bf16x8 a0 = *(const bf16x8*)(p);
  bf16x8 a1 = *(const bf16x8*)(p + 8);
  bf16x8 b0 = *(const bf16x8*)(p + 1024);
  bf16x8 b1 = *(const bf16x8*)(p + 1032);
  #pragma unroll
  for (int j = 0; j < 8; ++j) {
    float x0 = (float)a0[j], x1 = (float)a1[j];
    float y0 = (float)b0[j], y1 = (float)b1[j];
    sq += x0 * x0 + x1 * x1;
    sk += y0 * y0 + y1 * y1;
  }
  #pragma unroll
  for (int m = 1; m <= 32; m <<= 1) {
    sq += __shfl_xor(sq, m);
    sk += __shfl_xor(sk, m);
  }
  if (lane == 0) {
    invq[row] = 0.125f / fmaxf(sqrtf(sq), 1e-12f);   // scale/max(||q||,eps)
    invk[row] = 0.125f / fmaxf(sqrtf(sk), 1e-12f);
  }
}

// ---------------- head split + normalize + V transpose --------------------
// Qh: [B,H,N,64] = q_hat*0.125
// Kh: [B,H,N,64] = k_hat*0.125*log2(e)/T[h]   (so QK^T is exp2-ready)
// Vt: [B,H,64,N]
__global__ __launch_bounds__(256) void k_scatter(
    const bf16* __restrict__ qkv, const float* __restrict__ invq,
    const float* __restrict__ invk, const float* __restrict__ temperature,
    bf16* __restrict__ Qh, bf16* __restrict__ Kh, bf16* __restrict__ Vt)
{
  __shared__ __align__(16) bf16 vt[64][72];
  const int t = threadIdx.x;
  const int b = blockIdx.z, h = blockIdx.y;
  const int n0 = blockIdx.x * 64;
  const float tfac = 1.4426950408889634f / temperature[h];  // log2(e)/T
  {
    const int nl = t >> 2;
    const int d0 = (t & 3) << 4;
    const size_t row = (size_t)b * 2048 + n0 + nl;
    const bf16* src = qkv + row * 3072 + h * 64 + d0;
    const float fq = invq[row];
    const float fk = invk[row] * tfac;
    bf16x8 q0 = *(const bf16x8*)(src);
    bf16x8 q1 = *(const bf16x8*)(src + 8);
    bf16x8 k0 = *(const bf16x8*)(src + 1024);
    bf16x8 k1 = *(const bf16x8*)(src + 1032);
    bf16x8 v0 = *(const bf16x8*)(src + 2048);
    bf16x8 v1 = *(const bf16x8*)(src + 2056);
    bf16x8 qo, ko;
    #pragma unroll
    for (int j = 0; j < 8; ++j) {
      qo[j] = (bf16)((float)q0[j] * fq);
      ko[j] = (bf16)((float)k0[j] * fk);
    }
    size_t orow = ((size_t)(b * 16 + h) * 2048 + n0 + nl) * 64 + d0;
    *(bf16x8*)(Qh + orow) = qo;
    *(bf16x8*)(Kh + orow) = ko;
    #pragma unroll
    for (int j = 0; j < 8; ++j) {
      qo[j] = (bf16)((float)q1[j] * fq);
      ko[j] = (bf16)((float)k1[j] * fk);
    }
    *(bf16x8*)(Qh + orow + 8) = qo;
    *(bf16x8*)(Kh + orow + 8) = ko;
    *(bf16x8*)&vt[nl][d0] = v0;
    *(bf16x8*)&vt[nl][d0 + 8] = v1;
  }
  __syncthreads();
  {
    const int d = t >> 2;
    const int nc = (t & 3) << 4;
    bf16x8 o0, o1;
    #pragma unroll
    for (int j = 0; j < 8; ++j) { o0[j] = vt[nc + j][d]; o1[j] = vt[nc + 8 + j][d]; }
    size_t obase = ((size_t)(b * 16 + h) * 64 + d) * 2048 + n0 + nc;
    *(bf16x8*)(Vt + obase) = o0;
    *(bf16x8*)(Vt + obase + 8) = o1;
  }
}

// ---------------- flash attention: counted-vmcnt pipeline (T4) -------------
// R7 structure (8 waves, q-tile 128, shared staged K/V, XOR swizzle,
// max-free softmax) with the per-iter full vmcnt(0) drain REMOVED:
// triple-buffered K/V, prefetch depth 2, loop head = s_waitcnt vmcnt(2)
// (own oldest 2 loads = tile t, in-order per m135) + raw s_barrier ->
// tile t visible block-wide while tile t+1's loads stay in flight across
// the barrier (never drain to 0 in the main loop). STAGE(t+2) issues after
// the barrier (all waves are past compute(t-1), so overwriting buffer
// (t+2)%3 is safe); own ds_reads complete before barrier arrival via the
// compiler's lgkmcnt waits feeding MFMAs. LDS 64KB -> 2 blocks/CU.
__global__ __launch_bounds__(512, 4) void k_attn(
    const bf16* __restrict__ Qh, const bf16* __restrict__ Kh,
    const bf16* __restrict__ Vt, bf16* __restrict__ ao)
{
  __shared__ __align__(16) bf16 Kb[3][64 * 64];   // [kv][d], swizzled slots
  __shared__ __align__(16) bf16 Vb[3][64 * 64];   // [d][kv], swizzled slots
  __shared__ __align__(16) bf16 Pl[8][16 * 64];   // per-wave P, swizzled
  const int t = threadIdx.x, lane = t & 63, wv = t >> 6;
  const int l15 = lane & 15, l4 = lane >> 4;

  const int bid = blockIdx.x;                       // 0..511
  const int swz = (bid & 7) * 64 + (bid >> 3);      // XCD-chunked, bijective
  const int plane_id = swz >> 4;                    // b*16+h
  const int qb = swz & 15;
  const int b = plane_id >> 4, h = plane_id & 15;
  const int q0 = qb * 128 + wv * 16;

  const size_t plane = (size_t)plane_id * (2048 * 64);
  const bf16* Qp = Qh + plane;
  const bf16* Kp = Kh + plane;
  const bf16* Vp = Vt + plane;

  // staging: thread t owns 16B chunk t of each 8KB tile (64 rows x 128B).
  // row = t>>3, slot = t&7; slot holds global chunk sc = slot ^ (row&7).
  const int srow = t >> 3;
  const int sc = (t & 7) ^ (srow & 7);
  const bf16* gK = Kp + (size_t)srow * 64 + sc * 8;     // + kv0*64
  const bf16* gV = Vp + (size_t)srow * 2048 + sc * 8;   // + kv0

  bf16x8 qf0 = *(const bf16x8*)(Qp + (q0 + l15) * 64 + l4 * 8);
  bf16x8 qf1 = *(const bf16x8*)(Qp + (q0 + l15) * 64 + 32 + l4 * 8);

  bf16x8 vones;
  #pragma unroll
  for (int j = 0; j < 8; ++j) vones[j] = (bf16)1.0f;

  f32x4 accO[4];
  #pragma unroll
  for (int df = 0; df < 4; ++df) accO[df] = (f32x4){0.f, 0.f, 0.f, 0.f};
  f32x4 accS = (f32x4){0.f, 0.f, 0.f, 0.f};

  bf16* pw = &Pl[wv][0] + l15 * 64;       // this lane's P row base
  const int pxor = (l15 & 7) << 3;        // P swizzle (elems)

#define STAGE(bi, kv0_)                                                     \
  do {                                                                      \
    gload_lds16(gK + (size_t)(kv0_) * 64, (char*)&Kb[bi][0] + wv * 1024);   \
    gload_lds16(gV + (kv0_),              (char*)&Vb[bi][0] + wv * 1024);   \
  } while (0)

  STAGE(0, 0);       // 2 loads in flight
  STAGE(1, 64);      // 4 loads in flight

  int cur = 0;       // buffer of tile kt; stage target = (cur+2)%3
  for (int kt = 0; kt < 32; ++kt) {
    // wait own tile-kt loads (oldest 2); keep tile kt+1's in flight
    if (kt < 31) asm volatile("s_waitcnt vmcnt(2)" ::: "memory");
    else         asm volatile("s_waitcnt vmcnt(0)" ::: "memory");
    __builtin_amdgcn_s_barrier();        // tile kt visible block-wide
    __builtin_amdgcn_sched_barrier(0);

    const int stg = cur >= 1 ? cur - 1 : 2;        // (cur+2)%3
    if (kt < 30) STAGE(stg, (kt + 2) * 64);        // overlaps compute

    const bf16* kb = &Kb[cur][0];
    const bf16* vb = &Vb[cur][0];

    // QK^T (swapped): S[kv=(l>>4)*4+r][q=l15]
    f32x4 s[4];
    __builtin_amdgcn_s_setprio(1);
    #pragma unroll
    for (int kvf = 0; kvf < 4; ++kvf) {
      const int row = kvf * 16 + l15;
      const int r7 = row & 7;
      bf16x8 kf0 = *(const bf16x8*)(kb + row * 64 + ((l4 ^ r7) * 8));
      bf16x8 kf1 = *(const bf16x8*)(kb + row * 64 + (((4 + l4) ^ r7) * 8));
      s[kvf] = (f32x4){0.f, 0.f, 0.f, 0.f};
      s[kvf] = __builtin_amdgcn_mfma_f32_16x16x32_bf16(kf0, qf0, s[kvf], 0, 0, 0);
      s[kvf] = __builtin_amdgcn_mfma_f32_16x16x32_bf16(kf1, qf1, s[kvf], 0, 0, 0);
    }
    __builtin_amdgcn_s_setprio(0);
    // P = exp2(S) -> bf16 pairs -> swizzled per-wave LDS row
    #pragma unroll
    for (int kvf = 0; kvf < 4; ++kvf)
      #pragma unroll
      for (int rp = 0; rp < 2; ++rp) {
        bf16x2 pv = {(bf16)exp2_fast(s[kvf][2 * rp]),
                     (bf16)exp2_fast(s[kvf][2 * rp + 1])};
        *(bf16x2*)(pw + ((kvf * 16 + l4 * 4 + 2 * rp) ^ pxor)) = pv;
      }
    // PV + denominator (A = P from LDS, B = V from LDS)
    __builtin_amdgcn_s_setprio(1);
    #pragma unroll
    for (int ss = 0; ss < 2; ++ss) {
      bf16x8 pf = *(const bf16x8*)(pw + (((ss * 32 + l4 * 8)) ^ pxor));
      accS = __builtin_amdgcn_mfma_f32_16x16x32_bf16(pf, vones, accS, 0, 0, 0);
      #pragma unroll
      for (int df = 0; df < 4; ++df) {
        const int row = df * 16 + l15;
        bf16x8 vf = *(const bf16x8*)(vb + row * 64 + (((ss * 4 + l4) ^ (row & 7)) * 8));
        accO[df] = __builtin_amdgcn_mfma_f32_16x16x32_bf16(pf, vf, accO[df], 0, 0, 0);
      }
    }
    __builtin_amdgcn_s_setprio(0);
    cur = cur == 2 ? 0 : cur + 1;
  }
#undef STAGE

  // finalize: O = accO / rowsum; accS[r] holds the q-row sum in every lane.
  #pragma unroll
  for (int r = 0; r < 4; ++r) {
    const float inv = 1.f / accS[r];
    const size_t orow = ((size_t)b * 2048 + q0 + l4 * 4 + r) * 1024 + h * 64;
    #pragma unroll
    for (int df = 0; df < 4; ++df)
      ao[orow + df * 16 + l15] = (bf16)(accO[df][r] * inv);
  }
}

// --------------------------------------------------------------------------
extern "C" void kernel_launch(void* const* d_in, const int* in_sizes, int n_in,
                              void* d_out, int out_size, void* d_ws, size_t ws_size,
                              hipStream_t stream)
{
  (void)in_sizes; (void)n_in; (void)out_size; (void)ws_size;
  const float* x      = (const float*)d_in[0];   // [2,2048,1024]
  const float* qkv_w  = (const float*)d_in[1];   // [3072,1024]
  const float* temp   = (const float*)d_in[2];   // [16,1,1]
  const float* proj_w = (const float*)d_in[3];   // [1024,1024]
  const float* proj_b = (const float*)d_in[4];   // [1024]
  float* out = (float*)d_out;                    // [2,2048,1024] fp32

  char* w = (char*)d_ws;
  auto take = [&](size_t bytes) { char* p = w; w += (bytes + 255) & ~(size_t)255; return p; };
  bf16*  xb    = (bf16*)take((size_t)4096 * 1024 * 2);   // x bf16
  bf16*  wqkvb = (bf16*)take((size_t)3072 * 1024 * 2);   // qkv_w bf16
  bf16*  wpb   = (bf16*)take((size_t)1024 * 1024 * 2);   // proj_w bf16
  bf16*  qkvb  = (bf16*)take((size_t)4096 * 3072 * 2);   // qkv out bf16
  float* invq  = (float*)take((size_t)4096 * 4);
  float* invk  = (float*)take((size_t)4096 * 4);
  bf16*  Qh    = (bf16*)take((size_t)32 * 2048 * 64 * 2);
  bf16*  Kh    = (bf16*)take((size_t)32 * 2048 * 64 * 2);
  bf16*  Vt    = (bf16*)take((size_t)32 * 64 * 2048 * 2);
  bf16*  ao    = (bf16*)take((size_t)4096 * 1024 * 2);

  k_cvt3<<<8192, 256, 0, stream>>>(x, xb, qkv_w, wqkvb, proj_w, wpb);
  k_gemm_bt<1, 0><<<dim3(32, 24), 256, 0, stream>>>(xb, wqkvb, nullptr, qkvb, 1024, 3072);
  k_rownorm<<<1024, 256, 0, stream>>>(qkvb, invq, invk);
  k_scatter<<<dim3(32, 16, 2), 256, 0, stream>>>(qkvb, invq, invk, temp, Qh, Kh, Vt);
  k_attn<<<512, 512, 0, stream>>>(Qh, Kh, Vt, ao);
  k_gemm_bt<0, 1><<<dim3(32, 8), 256, 0, stream>>>(ao, wpb, proj_b, out, 1024, 1024);
}

// Round 13
// 202.205 us; speedup vs baseline: 1.0092x; 1.0092x over previous
//
#include <hip/hip_runtime.h>

typedef __bf16 bf16;
using bf16x2 = __attribute__((ext_vector_type(2))) bf16;
using bf16x4 = __attribute__((ext_vector_type(4))) bf16;
using bf16x8 = __attribute__((ext_vector_type(8))) bf16;
using f32x4  = __attribute__((ext_vector_type(4))) float;

#define DEVI __device__ __forceinline__

DEVI void gload_lds16(const void* g, void* l) {
  __builtin_amdgcn_global_load_lds((const __attribute__((address_space(1))) void*)g,
                                   (__attribute__((address_space(3))) void*)l, 16, 0, 0);
}

DEVI float exp2_fast(float x) { return __builtin_amdgcn_exp2f(x); }  // v_exp_f32

// ---------------- fp32 -> bf16 convert, all three inputs in one launch -----
__global__ __launch_bounds__(256) void k_cvt3(
    const float* __restrict__ a, bf16* __restrict__ oa,
    const float* __restrict__ b, bf16* __restrict__ ob,
    const float* __restrict__ c, bf16* __restrict__ oc) {
  const int blk = blockIdx.x;
  const float* in; bf16* out; int i;
  if (blk < 4096)      { in = a; out = oa; i = blk * 256 + threadIdx.x; }
  else if (blk < 7168) { in = b; out = ob; i = (blk - 4096) * 256 + threadIdx.x; }
  else                 { in = c; out = oc; i = (blk - 7168) * 256 + threadIdx.x; }
  f32x4 v = ((const f32x4*)in)[i];
  bf16x4 o = {(bf16)v.x, (bf16)v.y, (bf16)v.z, (bf16)v.w};
  ((bf16x4*)out)[i] = o;
}

// ---------------- GEMM: out[m,n] = sum_k A[m,k]*W[n,k] (+bias) ------------
// 128x128 tile, BK=64 (halves barrier-drain events vs BK=32 -- m233: the
// stage+vmcnt+barrier path is ~72% of the 2-phase gap), 4 waves (2x2 of
// 64x64), global_load_lds width=16. LDS rows are 128B so fragment reads
// use the attn-proven XOR slot-swizzle (pre-swizzled global source +
// swizzled ds_read) -> conflict-free b128. XCD-bijective block swizzle.
template<int OUT_BF16, int HAS_BIAS>
__global__ __launch_bounds__(256) void k_gemm_bt(
    const bf16* __restrict__ A, const bf16* __restrict__ W,
    const float* __restrict__ bias, void* __restrict__ outp,
    int Kk, int Nout)
{
  __shared__ __align__(16) bf16 As[128 * 64];
  __shared__ __align__(16) bf16 Bs[128 * 64];
  const int t = threadIdx.x;
  const int lane = t & 63, wv = t >> 6;
  const int l15 = lane & 15, l4 = lane >> 4;
  // XCD swizzle: fb -> (xcd = fb&7) gets contiguous chunk of cpx blocks
  const int nbx = gridDim.x;
  const int fb = blockIdx.y * nbx + blockIdx.x;
  const int cpx = (nbx * gridDim.y) >> 3;
  const int swz = (fb & 7) * cpx + (fb >> 3);
  const int row0 = (swz % nbx) * 128, col0 = (swz / nbx) * 128;
  const int wr = wv >> 1, wc = wv & 1;

  f32x4 acc[4][4];
  #pragma unroll
  for (int m = 0; m < 4; ++m)
    #pragma unroll
    for (int n = 0; n < 4; ++n) acc[m][n] = (f32x4){0.f, 0.f, 0.f, 0.f};

  // staging: 1024 chunks of 16B per 128x64 tile; thread t owns chunks
  // t + j*256. chunk c: row = c>>3, slot = c&7; slot holds global 16B-chunk
  // sc = slot ^ (row&7)  (pre-swizzled source, linear LDS dest).
  const bf16* gA[4];
  const bf16* gB[4];
  #pragma unroll
  for (int j = 0; j < 4; ++j) {
    const int c = t + j * 256;
    const int row = c >> 3;
    const int sc = (c & 7) ^ (row & 7);
    gA[j] = A + (size_t)(row0 + row) * Kk + sc * 8;
    gB[j] = W + (size_t)(col0 + row) * Kk + sc * 8;
  }

  const int nk = Kk >> 6;
  for (int kt = 0; kt < nk; ++kt) {
    __syncthreads();
    #pragma unroll
    for (int j = 0; j < 4; ++j) {
      gload_lds16(gA[j] + kt * 64, (char*)As + wv * 1024 + j * 4096);
      gload_lds16(gB[j] + kt * 64, (char*)Bs + wv * 1024 + j * 4096);
    }
    __syncthreads();
    bf16x8 af[4][2], bfv[4][2];
    #pragma unroll
    for (int m = 0; m < 4; ++m) {
      const int r = wr * 64 + m * 16 + l15;
      const int r7 = r & 7;
      af[m][0] = *(const bf16x8*)(As + r * 64 + ((l4 ^ r7) * 8));
      af[m][1] = *(const bf16x8*)(As + r * 64 + (((4 + l4) ^ r7) * 8));
    }
    #pragma unroll
    for (int n = 0; n < 4; ++n) {
      const int r = wc * 64 + n * 16 + l15;
      const int r7 = r & 7;
      bfv[n][0] = *(const bf16x8*)(Bs + r * 64 + ((l4 ^ r7) * 8));
      bfv[n][1] = *(const bf16x8*)(Bs + r * 64 + (((4 + l4) ^ r7) * 8));
    }
    #pragma unroll
    for (int s = 0; s < 2; ++s)
      #pragma unroll
      for (int m = 0; m < 4; ++m)
        #pragma unroll
        for (int n = 0; n < 4; ++n)
          acc[m][n] = __builtin_amdgcn_mfma_f32_16x16x32_bf16(af[m][s], bfv[n][s], acc[m][n], 0, 0, 0);
  }

  // epilogue: D[row=(l>>4)*4+r][col=l&15] (m89-verified mapping)
  #pragma unroll
  for (int n = 0; n < 4; ++n) {
    const int col = col0 + wc * 64 + n * 16 + l15;
    float bv = HAS_BIAS ? bias[col] : 0.f;
    #pragma unroll
    for (int m = 0; m < 4; ++m) {
      #pragma unroll
      for (int r = 0; r < 4; ++r) {
        const int row = row0 + wr * 64 + m * 16 + l4 * 4 + r;
        float v = acc[m][n][r] + bv;
        if (OUT_BF16) ((bf16*)outp)[(size_t)row * Nout + col] = (bf16)v;
        else          ((float*)outp)[(size_t)row * Nout + col] = v;
      }
    }
  }
}

// ---------------- fused L2-norm + head split + V transpose -----------------
// Phase 1: wave wv computes ||q||,||k|| for rows r0+wv*16..+15 (k_rownorm
// body verbatim, results to LDS). Phase 2: per head (4 per block via
// blockIdx.y), the proven scatter body with fq/fk from LDS. Saves the
// separate rownorm launch + its HBM pass (phase-2 re-reads are L2-hot).
// Qh: [B,H,N,64] = q_hat*0.125;  Kh = k_hat*0.125*log2(e)/T[h];  Vt: [B,H,64,N]
__global__ __launch_bounds__(256) void k_normscatter(
    const bf16* __restrict__ qkv, const float* __restrict__ temperature,
    bf16* __restrict__ Qh, bf16* __restrict__ Kh, bf16* __restrict__ Vt)
{
  __shared__ float invq_s[64], invk_s[64];
  __shared__ __align__(16) bf16 vt[64][72];
  const int t = threadIdx.x, lane = t & 63, wv = t >> 6;
  const int r0 = blockIdx.x * 64;                 // global row block
  // ---- phase 1: norms ----
  for (int rr = 0; rr < 16; ++rr) {
    const int row = r0 + wv * 16 + rr;
    const bf16* p = qkv + (size_t)row * 3072 + lane * 16;
    float sq = 0.f, sk = 0.f;
    bf16x8 a0 = *(const bf16x8*)(p);
    bf16x8 a1 = *(const bf16x8*)(p + 8);
    bf16x8 b0 = *(const bf16x8*)(p + 1024);
    bf16x8 b1 = *(const bf16x8*)(p + 1032);
    #pragma unroll
    for (int j = 0; j < 8; ++j) {
      float x0 = (float)a0[j], x1 = (float)a1[j];
      float y0 = (float)b0[j], y1 = (float)b1[j];
      sq += x0 * x0 + x1 * x1;
      sk += y0 * y0 + y1 * y1;
    }
    #pragma unroll
    for (int m = 1; m <= 32; m <<= 1) {
      sq += __shfl_xor(sq, m);
      sk += __shfl_xor(sk, m);
    }
    if (lane == 0) {
      invq_s[wv * 16 + rr] = 0.125f / fmaxf(sqrtf(sq), 1e-12f);
      invk_s[wv * 16 + rr] = 0.125f / fmaxf(sqrtf(sk), 1e-12f);
    }
  }
  __syncthreads();
  // ---- phase 2: scatter, 4 heads ----
  const int b = r0 >> 11;
  const int n0 = r0 & 2047;
  const int nl = t >> 2;
  const int d0 = (t & 3) << 4;
  const int d = t >> 2;
  const int nc = (t & 3) << 4;
  for (int hi = 0; hi < 4; ++hi) {
    const int h = blockIdx.y * 4 + hi;
    const float tfac = 1.4426950408889634f / temperature[h];  // log2(e)/T
    {
      const size_t row = (size_t)r0 + nl;
      const bf16* src = qkv + row * 3072 + h * 64 + d0;
      const float fq = invq_s[nl];
      const float fk = invk_s[nl] * tfac;
      bf16x8 q0 = *(const bf16x8*)(src);
      bf16x8 q1 = *(const bf16x8*)(src + 8);
      bf16x8 k0 = *(const bf16x8*)(src + 1024);
      bf16x8 k1 = *(const bf16x8*)(src + 1032);
      bf16x8 v0 = *(const bf16x8*)(src + 2048);
      bf16x8 v1 = *(const bf16x8*)(src + 2056);
      bf16x8 qo, ko;
      #pragma unroll
      for (int j = 0; j < 8; ++j) {
        qo[j] = (bf16)((float)q0[j] * fq);
        ko[j] = (bf16)((float)k0[j] * fk);
      }
      size_t orow = ((size_t)(b * 16 + h) * 2048 + n0 + nl) * 64 + d0;
      *(bf16x8*)(Qh + orow) = qo;
      *(bf16x8*)(Kh + orow) = ko;
      #pragma unroll
      for (int j = 0; j < 8; ++j) {
        qo[j] = (bf16)((float)q1[j] * fq);
        ko[j] = (bf16)((float)k1[j] * fk);
      }
      *(bf16x8*)(Qh + orow + 8) = qo;
      *(bf16x8*)(Kh + orow + 8) = ko;
      *(bf16x8*)&vt[nl][d0] = v0;
      *(bf16x8*)&vt[nl][d0 + 8] = v1;
    }
    __syncthreads();
    {
      bf16x8 o0, o1;
      #pragma unroll
      for (int j = 0; j < 8; ++j) { o0[j] = vt[nc + j][d]; o1[j] = vt[nc + 8 + j][d]; }
      size_t obase = ((size_t)(b * 16 + h) * 64 + d) * 2048 + n0 + nc;
      *(bf16x8*)(Vt + obase) = o0;
      *(bf16x8*)(Vt + obase + 8) = o1;
    }
    __syncthreads();   // vt reusable for next head
  }
}

// ---------------- flash attention (R9 config: best measured, 47.3us) ------
// 512 threads / 8 waves; q-tile 128 rows (16/wave) share one staged K/V
// tile; 2 blocks/CU = 16 waves/CU. 2-phase pipeline: stage NEXT K/V
// (global_load_lds, dbuf) before computing current; one __syncthreads
// (vmcnt drain) per iter. XOR slot-swizzle on K/V. Max-free softmax
// (|S| <= log2e/(64 T) by construction), denominator via all-ones MFMA.
// setprio(1) around MFMA clusters. Grid 512 = 8 XCDs x 64, bijective.
__global__ __launch_bounds__(512, 4) void k_attn(
    const bf16* __restrict__ Qh, const bf16* __restrict__ Kh,
    const bf16* __restrict__ Vt, bf16* __restrict__ ao)
{
  __shared__ __align__(16) bf16 Kb[2][64 * 64];   // [kv][d], swizzled slots
  __shared__ __align__(16) bf16 Vb[2][64 * 64];   // [d][kv], swizzled slots
  __shared__ __align__(16) bf16 Pl[8][16 * 64];   // per-wave P, swizzled
  const int t = threadIdx.x, lane = t & 63, wv = t >> 6;
  const int l15 = lane & 15, l4 = lane >> 4;

  const int bid = blockIdx.x;                       // 0..511
  const int swz = (bid & 7) * 64 + (bid >> 3);      // XCD-chunked, bijective
  const int plane_id = swz >> 4;                    // b*16+h
  const int qb = swz & 15;
  const int b = plane_id >> 4, h = plane_id & 15;
  const int q0 = qb * 128 + wv * 16;

  const size_t plane = (size_t)plane_id * (2048 * 64);
  const bf16* Qp = Qh + plane;
  const bf16* Kp = Kh + plane;
  const bf16* Vp = Vt + plane;

  // staging: thread t owns 16B chunk t of each 8KB tile (64 rows x 128B).
  // row = t>>3, slot = t&7; slot holds global chunk sc = slot ^ (row&7).
  const int srow = t >> 3;
  const int sc = (t & 7) ^ (srow & 7);
  const bf16* gK = Kp + (size_t)srow * 64 + sc * 8;     // + kv0*64
  const bf16* gV = Vp + (size_t)srow * 2048 + sc * 8;   // + kv0
  char* lK0 = (char*)&Kb[0][0] + wv * 1024;             // lane*16 added by HW
  char* lK1 = (char*)&Kb[1][0] + wv * 1024;
  char* lV0 = (char*)&Vb[0][0] + wv * 1024;
  char* lV1 = (char*)&Vb[1][0] + wv * 1024;

  bf16x8 qf0 = *(const bf16x8*)(Qp + (q0 + l15) * 64 + l4 * 8);
  bf16x8 qf1 = *(const bf16x8*)(Qp + (q0 + l15) * 64 + 32 + l4 * 8);

  bf16x8 vones;
  #pragma unroll
  for (int j = 0; j < 8; ++j) vones[j] = (bf16)1.0f;

  f32x4 accO[4];
  #pragma unroll
  for (int df = 0; df < 4; ++df) accO[df] = (f32x4){0.f, 0.f, 0.f, 0.f};
  f32x4 accS = (f32x4){0.f, 0.f, 0.f, 0.f};

  bf16* pw = &Pl[wv][0] + l15 * 64;       // this lane's P row base
  const int pxor = (l15 & 7) << 3;        // P swizzle (elems)

#define STAGE(bi, kv0_)                                           \
  do {                                                            \
    gload_lds16(gK + (size_t)(kv0_) * 64, (bi) ? lK1 : lK0);      \
    gload_lds16(gV + (kv0_),              (bi) ? lV1 : lV0);      \
  } while (0)

  STAGE(0, 0);
  __syncthreads();   // drains vmcnt: tile 0 resident

  int cur = 0;
  for (int kt = 0; kt < 32; ++kt) {
    if (kt < 31) STAGE(cur ^ 1, (kt + 1) * 64);   // prefetch overlaps compute

    const bf16* kb = &Kb[cur][0];
    const bf16* vb = &Vb[cur][0];

    // QK^T (swapped): S[kv=(l>>4)*4+r][q=l15]
    f32x4 s[4];
    __builtin_amdgcn_s_setprio(1);
    #pragma unroll
    for (int kvf = 0; kvf < 4; ++kvf) {
      const int row = kvf * 16 + l15;
      const int r7 = row & 7;
      bf16x8 kf0 = *(const bf16x8*)(kb + row * 64 + ((l4 ^ r7) * 8));
      bf16x8 kf1 = *(const bf16x8*)(kb + row * 64 + (((4 + l4) ^ r7) * 8));
      s[kvf] = (f32x4){0.f, 0.f, 0.f, 0.f};
      s[kvf] = __builtin_amdgcn_mfma_f32_16x16x32_bf16(kf0, qf0, s[kvf], 0, 0, 0);
      s[kvf] = __builtin_amdgcn_mfma_f32_16x16x32_bf16(kf1, qf1, s[kvf], 0, 0, 0);
    }
    __builtin_amdgcn_s_setprio(0);
    // P = exp2(S) -> bf16 pairs -> swizzled per-wave LDS row
    #pragma unroll
    for (int kvf = 0; kvf < 4; ++kvf)
      #pragma unroll
      for (int rp = 0; rp < 2; ++rp) {
        bf16x2 pv = {(bf16)exp2_fast(s[kvf][2 * rp]),
                     (bf16)exp2_fast(s[kvf][2 * rp + 1])};
        *(bf16x2*)(pw + ((kvf * 16 + l4 * 4 + 2 * rp) ^ pxor)) = pv;
      }
    // PV + denominator (A = P from LDS, B = V from LDS)
    __builtin_amdgcn_s_setprio(1);
    #pragma unroll
    for (int ss = 0; ss < 2; ++ss) {
      bf16x8 pf = *(const bf16x8*)(pw + (((ss * 32 + l4 * 8)) ^ pxor));
      accS = __builtin_amdgcn_mfma_f32_16x16x32_bf16(pf, vones, accS, 0, 0, 0);
      #pragma unroll
      for (int df = 0; df < 4; ++df) {
        const int row = df * 16 + l15;
        bf16x8 vf = *(const bf16x8*)(vb + row * 64 + (((ss * 4 + l4) ^ (row & 7)) * 8));
        accO[df] = __builtin_amdgcn_mfma_f32_16x16x32_bf16(pf, vf, accO[df], 0, 0, 0);
      }
    }
    __builtin_amdgcn_s_setprio(0);
    __syncthreads();   // readers done + prefetch drained (vmcnt 0)
    cur ^= 1;
  }
#undef STAGE

  // finalize: O = accO / rowsum; accS[r] holds the q-row sum in every lane.
  #pragma unroll
  for (int r = 0; r < 4; ++r) {
    const float inv = 1.f / accS[r];
    const size_t orow = ((size_t)b * 2048 + q0 + l4 * 4 + r) * 1024 + h * 64;
    #pragma unroll
    for (int df = 0; df < 4; ++df)
      ao[orow + df * 16 + l15] = (bf16)(accO[df][r] * inv);
  }
}

// --------------------------------------------------------------------------
extern "C" void kernel_launch(void* const* d_in, const int* in_sizes, int n_in,
                              void* d_out, int out_size, void* d_ws, size_t ws_size,
                              hipStream_t stream)
{
  (void)in_sizes; (void)n_in; (void)out_size; (void)ws_size;
  const float* x      = (const float*)d_in[0];   // [2,2048,1024]
  const float* qkv_w  = (const float*)d_in[1];   // [3072,1024]
  const float* temp   = (const float*)d_in[2];   // [16,1,1]
  const float* proj_w = (const float*)d_in[3];   // [1024,1024]
  const float* proj_b = (const float*)d_in[4];   // [1024]
  float* out = (float*)d_out;                    // [2,2048,1024] fp32

  char* w = (char*)d_ws;
  auto take = [&](size_t bytes) { char* p = w; w += (bytes + 255) & ~(size_t)255; return p; };
  bf16*  xb    = (bf16*)take((size_t)4096 * 1024 * 2);   // x bf16
  bf16*  wqkvb = (bf16*)take((size_t)3072 * 1024 * 2);   // qkv_w bf16
  bf16*  wpb   = (bf16*)take((size_t)1024 * 1024 * 2);   // proj_w bf16
  bf16*  qkvb  = (bf16*)take((size_t)4096 * 3072 * 2);   // qkv out bf16
  bf16*  Qh    = (bf16*)take((size_t)32 * 2048 * 64 * 2);
  bf16*  Kh    = (bf16*)take((size_t)32 * 2048 * 64 * 2);
  bf16*  Vt    = (bf16*)take((size_t)32 * 64 * 2048 * 2);
  bf16*  ao    = (bf16*)take((size_t)4096 * 1024 * 2);

  k_cvt3<<<8192, 256, 0, stream>>>(x, xb, qkv_w, wqkvb, proj_w, wpb);
  k_gemm_bt<1, 0><<<dim3(32, 24), 256, 0, stream>>>(xb, wqkvb, nullptr, qkvb, 1024, 3072);
  k_normscatter<<<dim3(64, 4), 256, 0, stream>>>(qkvb, temp, Qh, Kh, Vt);
  k_attn<<<512, 512, 0, stream>>>(Qh, Kh, Vt, ao);
  k_gemm_bt<0, 1><<<dim3(32, 8), 256, 0, stream>>>(ao, wpb, proj_b, out, 1024, 1024);
}